// Round 3
// baseline (513.705 us; speedup 1.0000x reference)
//
#include <hip/hip_runtime.h>

#define N_NODES 4096
#define F_UAV 64
#define NOBS 262400
#define GCN_FLAT (N_NODES * F_UAV)   // 262144
#define HDIM 1024
#define N_ACT 64
#define N_EDGES 65536

typedef float f32x4 __attribute__((ext_vector_type(4)));

// ---- workspace layout (float offsets) ----
#define OFF_X      0                         // 262400
#define OFF_H      262400                    // 262144
#define OFF_DINV   (OFF_H + GCN_FLAT)        // 4096
#define OFF_DEG    (OFF_DINV + N_NODES)      // 4096 (int)
#define OFF_BASE   (OFF_DEG + N_NODES)       // 4096 (int)
#define OFF_CUR    (OFF_BASE + N_NODES)      // 4096 (int)
#define OFF_SSRC   (OFF_CUR + N_NODES)       // 65536 (int)
#define OFF_P1     (OFF_SSRC + N_EDGES)      // 1025*1024
#define OFF_Y1     (OFF_P1 + 1025*1024)      // 1024
#define OFF_P2     (OFF_Y1 + HDIM)           // 256*1024
#define OFF_Y2     (OFF_P2 + 256*1024)       // 1024

// h = node_x @ gcn_w  (4096x64 @ 64x64); also zeroes deg[]
__global__ __launch_bounds__(256) void k_gcn_h(const float* __restrict__ nx,
                                               const float* __restrict__ w,
                                               float* __restrict__ h,
                                               int* __restrict__ deg) {
    __shared__ float sw[F_UAV * F_UAV];
    __shared__ float sx4[256];
    int tid = threadIdx.x;
    if (blockIdx.x < 16) deg[blockIdx.x * 256 + tid] = 0;
    for (int i = tid; i < F_UAV * F_UAV; i += 256) sw[i] = w[i];
    sx4[tid] = nx[blockIdx.x * 256 + tid];
    __syncthreads();
    int r = tid >> 6, j = tid & 63;
    float acc = 0.f;
#pragma unroll
    for (int k = 0; k < F_UAV; ++k) acc += sx4[r * 64 + k] * sw[k * F_UAV + j];
    h[blockIdx.x * 256 + r * 64 + j] = acc;
}

__global__ void k_deg_count(const int* __restrict__ dst, int* deg) {
    int e = blockIdx.x * 256 + threadIdx.x;
    if (e < N_EDGES) atomicAdd(&deg[dst[e]], 1);
}

// single block, 1024 threads: exclusive prefix over deg -> base, cursor;
// dinv = rsqrt(deg+1); copy obs tail into x.
__global__ __launch_bounds__(1024) void k_prefix(const int* __restrict__ deg,
                                                 int* __restrict__ base,
                                                 int* __restrict__ cursor,
                                                 float* __restrict__ dinv,
                                                 const float* __restrict__ obs,
                                                 float* __restrict__ x) {
    __shared__ int ssum[1024];
    int t = threadIdx.x;
    int d0 = deg[4 * t], d1 = deg[4 * t + 1], d2 = deg[4 * t + 2], d3 = deg[4 * t + 3];
    int local = d0 + d1 + d2 + d3;
    ssum[t] = local;
    __syncthreads();
    for (int off = 1; off < 1024; off <<= 1) {
        int v = (t >= off) ? ssum[t - off] : 0;
        __syncthreads();
        ssum[t] += v;
        __syncthreads();
    }
    int excl = ssum[t] - local;
    int b0 = excl, b1 = b0 + d0, b2 = b1 + d1, b3 = b2 + d2;
    base[4 * t] = b0;   cursor[4 * t] = b0;
    base[4 * t + 1] = b1; cursor[4 * t + 1] = b1;
    base[4 * t + 2] = b2; cursor[4 * t + 2] = b2;
    base[4 * t + 3] = b3; cursor[4 * t + 3] = b3;
    dinv[4 * t]     = rsqrtf((float)(d0 + 1));
    dinv[4 * t + 1] = rsqrtf((float)(d1 + 1));
    dinv[4 * t + 2] = rsqrtf((float)(d2 + 1));
    dinv[4 * t + 3] = rsqrtf((float)(d3 + 1));
    if (t < NOBS - GCN_FLAT) x[GCN_FLAT + t] = obs[GCN_FLAT + t];
}

// bucket placement: ssrc[slot] = src  (slot via int atomic on cursor)
__global__ void k_place(const int* __restrict__ src, const int* __restrict__ dst,
                        int* __restrict__ cursor, int* __restrict__ ssrc) {
    int e = blockIdx.x * 256 + threadIdx.x;
    if (e < N_EDGES) {
        int slot = atomicAdd(&cursor[dst[e]], 1);
        ssrc[slot] = src[e];
    }
}

// gather per destination node: one wave per node (4 waves/block)
__global__ __launch_bounds__(256) void k_gather(const int* __restrict__ base,
                                                const int* __restrict__ deg,
                                                const int* __restrict__ ssrc,
                                                const float* __restrict__ h,
                                                const float* __restrict__ dinv,
                                                const float* __restrict__ gb,
                                                float* __restrict__ x) {
    int tid = threadIdx.x;
    int n = blockIdx.x * 4 + (tid >> 6);
    int j = tid & 63;
    int lo = base[n], cnt = deg[n];
    int end = lo + cnt;
    float acc0 = 0.f, acc1 = 0.f;
    int i = lo;
    for (; i + 1 < end; i += 2) {
        int s0 = ssrc[i], s1 = ssrc[i + 1];
        acc0 += h[s0 * 64 + j] * dinv[s0];
        acc1 += h[s1 * 64 + j] * dinv[s1];
    }
    if (i < end) {
        int s = ssrc[i];
        acc0 += h[s * 64 + j] * dinv[s];
    }
    float dn = dinv[n];
    x[n * 64 + j] = (acc0 + acc1) * dn + h[n * 64 + j] * dn * dn + gb[j];
}

// partial mat-vec: part[block][j] = sum over RPB rows of x[k]*W[k][j]
template <int RPB>
__global__ __launch_bounds__(256) void k_matvec_part(const float* __restrict__ x,
                                                     const float* __restrict__ W,
                                                     float* __restrict__ part) {
    __shared__ float sx[RPB];
    int tid = threadIdx.x;
    int k0 = blockIdx.x * RPB;
    for (int i = tid; i < RPB; i += 256) sx[i] = x[k0 + i];
    __syncthreads();
    f32x4 acc = {0.f, 0.f, 0.f, 0.f};
    const f32x4* Wr = ((const f32x4*)W) + (size_t)k0 * (HDIM / 4) + tid;
#pragma unroll 4
    for (int k = 0; k < RPB; ++k) {
        float xv = sx[k];
        f32x4 w = __builtin_nontemporal_load(&Wr[(size_t)k * (HDIM / 4)]);
        acc += xv * w;
    }
    *(f32x4*)(part + (size_t)blockIdx.x * HDIM + tid * 4) = acc;
}

// y[j] = (relu?)(b[j] + sum_c part[c][j]);  grid 4 x 256
__global__ void k_reduce(const float* __restrict__ part, const float* __restrict__ b,
                         float* __restrict__ y, int nparts, int do_relu) {
    int j = blockIdx.x * 256 + threadIdx.x;
    if (j >= HDIM) return;
    float acc = b[j];
    for (int c = 0; c < nparts; ++c) acc += part[(size_t)c * HDIM + j];
    if (do_relu) acc = fmaxf(acc, 0.f);
    y[j] = acc;
}

// value/advantage heads + dueling combine. single block, 256 threads.
__global__ __launch_bounds__(256) void k_heads(const float* __restrict__ y2,
                                               const float* __restrict__ wv,
                                               const float* __restrict__ bv,
                                               const float* __restrict__ wa,
                                               const float* __restrict__ ba,
                                               float* __restrict__ out) {
    __shared__ float s_adv[4][64];
    __shared__ float s_pv[256];
    int t = threadIdx.x;
    int a = t & 63, g = t >> 6;
    float pa = 0.f, pv = 0.f;
    for (int kk = 0; kk < 256; ++kk) {
        int k = g * 256 + kk;
        pa += y2[k] * wa[k * 64 + a];
    }
    for (int k = t; k < HDIM; k += 256) pv += y2[k] * wv[k];
    s_adv[g][a] = pa;
    s_pv[t] = pv;
    __syncthreads();
    if (t < 64) {
        float adv = ba[a] + s_adv[0][a] + s_adv[1][a] + s_adv[2][a] + s_adv[3][a];
        float v = s_pv[a] + s_pv[a + 64] + s_pv[a + 128] + s_pv[a + 192];
        for (int off = 32; off; off >>= 1) v += __shfl_xor(v, off);
        float m = adv;
        for (int off = 32; off; off >>= 1) m += __shfl_xor(m, off);
        m *= (1.f / 64.f);
        out[a] = (v + bv[0]) + adv - m;
    }
}

extern "C" void kernel_launch(void* const* d_in, const int* in_sizes, int n_in,
                              void* d_out, int out_size, void* d_ws, size_t ws_size,
                              hipStream_t stream) {
    const float* node_x   = (const float*)d_in[0];
    const float* flat_obs = (const float*)d_in[1];
    const float* gcn_w    = (const float*)d_in[2];
    const float* gcn_b    = (const float*)d_in[3];
    const float* w1       = (const float*)d_in[4];
    const float* b1       = (const float*)d_in[5];
    const float* w2       = (const float*)d_in[6];
    const float* b2       = (const float*)d_in[7];
    const float* wv       = (const float*)d_in[8];
    const float* bv       = (const float*)d_in[9];
    const float* wa       = (const float*)d_in[10];
    const float* ba       = (const float*)d_in[11];
    const int*   ei       = (const int*)d_in[12];   // x64 disabled -> int32
    const int* src = ei;
    const int* dst = ei + N_EDGES;

    float* ws   = (float*)d_ws;
    float* x    = ws + OFF_X;
    float* h    = ws + OFF_H;
    float* dinv = ws + OFF_DINV;
    int*   deg  = (int*)(ws + OFF_DEG);
    int*   base = (int*)(ws + OFF_BASE);
    int*   cur  = (int*)(ws + OFF_CUR);
    int*   ssrc = (int*)(ws + OFF_SSRC);
    float* p1   = ws + OFF_P1;
    float* y1   = ws + OFF_Y1;
    float* p2   = ws + OFF_P2;
    float* y2   = ws + OFF_Y2;
    float* out  = (float*)d_out;

    k_gcn_h<<<N_NODES / 4, 256, 0, stream>>>(node_x, gcn_w, h, deg);
    k_deg_count<<<N_EDGES / 256, 256, 0, stream>>>(dst, deg);
    k_prefix<<<1, 1024, 0, stream>>>(deg, base, cur, dinv, flat_obs, x);
    k_place<<<N_EDGES / 256, 256, 0, stream>>>(src, dst, cur, ssrc);
    k_gather<<<N_NODES / 4, 256, 0, stream>>>(base, deg, ssrc, h, dinv, gcn_b, x);

    // y1 = relu(x @ w1 + b1): 1025 blocks x 256 rows
    k_matvec_part<256><<<1025, 256, 0, stream>>>(x, w1, p1);
    k_reduce<<<4, 256, 0, stream>>>(p1, b1, y1, 1025, 1);

    // y2 = relu(y1 @ w2 + b2): 256 blocks x 4 rows
    k_matvec_part<4><<<256, 256, 0, stream>>>(y1, w2, p2);
    k_reduce<<<4, 256, 0, stream>>>(p2, b2, y2, 256, 1);

    k_heads<<<1, 256, 0, stream>>>(y2, wv, bv, wa, ba, out);
}

// Round 4
// 258.234 us; speedup vs baseline: 1.9893x; 1.9893x over previous
//
#include <hip/hip_runtime.h>

#define N_NODES 4096
#define F_UAV 64
#define NOBS 262400
#define GCN_FLAT (N_NODES * F_UAV)   // 262144
#define HDIM 1024
#define N_ACT 64
#define N_EDGES 65536

typedef float f32x4 __attribute__((ext_vector_type(4)));

// matvec1 partition: 2048 blocks, first 256 take 129 rows, remaining 1792 take 128.
// 256*129 + 1792*128 = 262400. nparts = 2048 (=128 segments of 16 for sum16).
#define MV1_GRID 2048
#define MV1_BIGN 256
#define MV1_BIG 129
#define MV1_SMALL 128

// ---- workspace layout (float offsets) ----
#define OFF_X      0                          // 262400
#define OFF_H      262400                     // 262144
#define OFF_DINV   (OFF_H + GCN_FLAT)         // 4096
#define OFF_DEG    (OFF_DINV + N_NODES)       // 4096 (int)
#define OFF_BASE   (OFF_DEG + N_NODES)        // 4096 (int)
#define OFF_CUR    (OFF_BASE + N_NODES)       // 4096 (int)
#define OFF_SSRC   (OFF_CUR + N_NODES)        // 65536 (int)
#define OFF_P1     (OFF_SSRC + N_EDGES)       // 2048*1024
#define OFF_Q1     (OFF_P1 + 2048*1024)       // 128*1024
#define OFF_Y1     (OFF_Q1 + 128*1024)        // 1024
#define OFF_P2     (OFF_Y1 + HDIM)            // 256*1024
#define OFF_Q2     (OFF_P2 + 256*1024)        // 16*1024

// h = node_x @ gcn_w  (4096x64 @ 64x64); also zeroes deg[]
__global__ __launch_bounds__(256) void k_gcn_h(const float* __restrict__ nx,
                                               const float* __restrict__ w,
                                               float* __restrict__ h,
                                               int* __restrict__ deg) {
    __shared__ float sw[F_UAV * F_UAV];
    __shared__ float sx4[256];
    int tid = threadIdx.x;
    if (blockIdx.x < 16) deg[blockIdx.x * 256 + tid] = 0;
    for (int i = tid; i < F_UAV * F_UAV; i += 256) sw[i] = w[i];
    sx4[tid] = nx[blockIdx.x * 256 + tid];
    __syncthreads();
    int r = tid >> 6, j = tid & 63;
    float acc = 0.f;
#pragma unroll
    for (int k = 0; k < F_UAV; ++k) acc += sx4[r * 64 + k] * sw[k * F_UAV + j];
    h[blockIdx.x * 256 + r * 64 + j] = acc;
}

__global__ void k_deg_count(const int* __restrict__ dst, int* deg) {
    int e = blockIdx.x * 256 + threadIdx.x;
    if (e < N_EDGES) atomicAdd(&deg[dst[e]], 1);
}

// single block, 1024 threads: exclusive prefix over deg -> base, cursor;
// dinv = rsqrt(deg+1); copy obs tail into x.
__global__ __launch_bounds__(1024) void k_prefix(const int* __restrict__ deg,
                                                 int* __restrict__ base,
                                                 int* __restrict__ cursor,
                                                 float* __restrict__ dinv,
                                                 const float* __restrict__ obs,
                                                 float* __restrict__ x) {
    __shared__ int ssum[1024];
    int t = threadIdx.x;
    int d0 = deg[4 * t], d1 = deg[4 * t + 1], d2 = deg[4 * t + 2], d3 = deg[4 * t + 3];
    int local = d0 + d1 + d2 + d3;
    ssum[t] = local;
    __syncthreads();
    for (int off = 1; off < 1024; off <<= 1) {
        int v = (t >= off) ? ssum[t - off] : 0;
        __syncthreads();
        ssum[t] += v;
        __syncthreads();
    }
    int excl = ssum[t] - local;
    int b0 = excl, b1 = b0 + d0, b2 = b1 + d1, b3 = b2 + d2;
    base[4 * t] = b0;     cursor[4 * t] = b0;
    base[4 * t + 1] = b1; cursor[4 * t + 1] = b1;
    base[4 * t + 2] = b2; cursor[4 * t + 2] = b2;
    base[4 * t + 3] = b3; cursor[4 * t + 3] = b3;
    dinv[4 * t]     = rsqrtf((float)(d0 + 1));
    dinv[4 * t + 1] = rsqrtf((float)(d1 + 1));
    dinv[4 * t + 2] = rsqrtf((float)(d2 + 1));
    dinv[4 * t + 3] = rsqrtf((float)(d3 + 1));
    if (t < NOBS - GCN_FLAT) x[GCN_FLAT + t] = obs[GCN_FLAT + t];
}

// bucket placement: ssrc[slot] = src
__global__ void k_place(const int* __restrict__ src, const int* __restrict__ dst,
                        int* __restrict__ cursor, int* __restrict__ ssrc) {
    int e = blockIdx.x * 256 + threadIdx.x;
    if (e < N_EDGES) {
        int slot = atomicAdd(&cursor[dst[e]], 1);
        ssrc[slot] = src[e];
    }
}

// gather per destination node: one wave per node (4 waves/block)
__global__ __launch_bounds__(256) void k_gather(const int* __restrict__ base,
                                                const int* __restrict__ deg,
                                                const int* __restrict__ ssrc,
                                                const float* __restrict__ h,
                                                const float* __restrict__ dinv,
                                                const float* __restrict__ gb,
                                                float* __restrict__ x) {
    int tid = threadIdx.x;
    int n = blockIdx.x * 4 + (tid >> 6);
    int j = tid & 63;
    int lo = base[n], cnt = deg[n];
    int end = lo + cnt;
    float acc0 = 0.f, acc1 = 0.f;
    int i = lo;
    for (; i + 1 < end; i += 2) {
        int s0 = ssrc[i], s1 = ssrc[i + 1];
        acc0 += h[s0 * 64 + j] * dinv[s0];
        acc1 += h[s1 * 64 + j] * dinv[s1];
    }
    if (i < end) {
        int s = ssrc[i];
        acc0 += h[s * 64 + j] * dinv[s];
    }
    float dn = dinv[n];
    x[n * 64 + j] = (acc0 + acc1) * dn + h[n * 64 + j] * dn * dn + gb[j];
}

// partial mat-vec, ragged block row-ranges (tail-free grid).
// block b: rows [k0, k0+cnt); thread t owns f32x4 of columns 4t..4t+3.
__global__ __launch_bounds__(256) void k_matvec(const float* __restrict__ x,
                                                const float* __restrict__ W,
                                                float* __restrict__ part,
                                                int big_n, int big_sz, int small_sz) {
    __shared__ float sx[132];
    int tid = threadIdx.x;
    int b = blockIdx.x;
    int k0 = (b < big_n) ? b * big_sz : big_n * big_sz + (b - big_n) * small_sz;
    int cnt = (b < big_n) ? big_sz : small_sz;
    for (int i = tid; i < cnt; i += 256) sx[i] = x[k0 + i];
    __syncthreads();
    f32x4 acc = {0.f, 0.f, 0.f, 0.f};
    const f32x4* Wr = ((const f32x4*)W) + (size_t)k0 * (HDIM / 4) + tid;
    int kk = cnt & ~7;
    int k = 0;
    for (; k < kk; k += 8) {
#pragma unroll
        for (int u = 0; u < 8; ++u) {
            float xv = sx[k + u];
            f32x4 w = Wr[(size_t)(k + u) * (HDIM / 4)];
            acc += xv * w;
        }
    }
    for (; k < cnt; ++k) acc += sx[k] * Wr[(size_t)k * (HDIM / 4)];
    ((f32x4*)(part + (size_t)b * HDIM))[tid] = acc;
}

// stage-A reduction: block s sums 16 consecutive partial rows -> q[s][*]
__global__ __launch_bounds__(256) void k_sum16(const float* __restrict__ part,
                                               float* __restrict__ q) {
    int t = threadIdx.x, s = blockIdx.x;
    const f32x4* p = ((const f32x4*)part) + (size_t)s * 16 * (HDIM / 4) + t;
    f32x4 acc = {0.f, 0.f, 0.f, 0.f};
#pragma unroll
    for (int r = 0; r < 16; ++r) acc += p[(size_t)r * (HDIM / 4)];
    ((f32x4*)q)[(size_t)s * (HDIM / 4) + t] = acc;
}

// stage-B: y1[j] = relu(b1[j] + sum_{s<128} q[s][j]);  grid 4 x 256
__global__ void k_finish128(const float* __restrict__ q, const float* __restrict__ b,
                            float* __restrict__ y) {
    int j = blockIdx.x * 256 + threadIdx.x;
    float acc = b[j];
#pragma unroll 8
    for (int s = 0; s < 128; ++s) acc += q[s * HDIM + j];
    y[j] = fmaxf(acc, 0.f);
}

// fused: y2 = relu(b2 + sum_{s<16} q2[s][*]) then dueling heads. 1 block x 1024.
__global__ __launch_bounds__(1024) void k_heads_f(const float* __restrict__ q2,
                                                  const float* __restrict__ b2,
                                                  const float* __restrict__ wv,
                                                  const float* __restrict__ bv,
                                                  const float* __restrict__ wa,
                                                  const float* __restrict__ ba,
                                                  float* __restrict__ out) {
    __shared__ float y2s[1024];
    __shared__ float s_adv[16][64];
    __shared__ float s_pv[1024];
    int t = threadIdx.x;
    float acc = b2[t];
#pragma unroll
    for (int s = 0; s < 16; ++s) acc += q2[s * HDIM + t];
    float y = fmaxf(acc, 0.f);
    y2s[t] = y;
    s_pv[t] = y * wv[t];
    __syncthreads();
    int g = t >> 6, a = t & 63;
    float pa = 0.f;
#pragma unroll 4
    for (int kk = 0; kk < 64; ++kk) pa += y2s[g * 64 + kk] * wa[(g * 64 + kk) * 64 + a];
    s_adv[g][a] = pa;
    __syncthreads();
    if (t < 64) {
        float adv = ba[a];
#pragma unroll
        for (int gg = 0; gg < 16; ++gg) adv += s_adv[gg][a];
        float v = 0.f;
#pragma unroll
        for (int i = 0; i < 16; ++i) v += s_pv[a + 64 * i];
        for (int off = 32; off; off >>= 1) v += __shfl_xor(v, off);
        float m = adv;
        for (int off = 32; off; off >>= 1) m += __shfl_xor(m, off);
        m *= (1.f / 64.f);
        out[a] = (v + bv[0]) + adv - m;
    }
}

extern "C" void kernel_launch(void* const* d_in, const int* in_sizes, int n_in,
                              void* d_out, int out_size, void* d_ws, size_t ws_size,
                              hipStream_t stream) {
    const float* node_x   = (const float*)d_in[0];
    const float* flat_obs = (const float*)d_in[1];
    const float* gcn_w    = (const float*)d_in[2];
    const float* gcn_b    = (const float*)d_in[3];
    const float* w1       = (const float*)d_in[4];
    const float* b1       = (const float*)d_in[5];
    const float* w2       = (const float*)d_in[6];
    const float* b2       = (const float*)d_in[7];
    const float* wv       = (const float*)d_in[8];
    const float* bv       = (const float*)d_in[9];
    const float* wa       = (const float*)d_in[10];
    const float* ba       = (const float*)d_in[11];
    const int*   ei       = (const int*)d_in[12];
    const int* src = ei;
    const int* dst = ei + N_EDGES;

    float* ws   = (float*)d_ws;
    float* x    = ws + OFF_X;
    float* h    = ws + OFF_H;
    float* dinv = ws + OFF_DINV;
    int*   deg  = (int*)(ws + OFF_DEG);
    int*   base = (int*)(ws + OFF_BASE);
    int*   cur  = (int*)(ws + OFF_CUR);
    int*   ssrc = (int*)(ws + OFF_SSRC);
    float* p1   = ws + OFF_P1;
    float* q1   = ws + OFF_Q1;
    float* y1   = ws + OFF_Y1;
    float* p2   = ws + OFF_P2;
    float* q2   = ws + OFF_Q2;
    float* out  = (float*)d_out;

    k_gcn_h<<<N_NODES / 4, 256, 0, stream>>>(node_x, gcn_w, h, deg);
    k_deg_count<<<N_EDGES / 256, 256, 0, stream>>>(dst, deg);
    k_prefix<<<1, 1024, 0, stream>>>(deg, base, cur, dinv, flat_obs, x);
    k_place<<<N_EDGES / 256, 256, 0, stream>>>(src, dst, cur, ssrc);
    k_gather<<<N_NODES / 4, 256, 0, stream>>>(base, deg, ssrc, h, dinv, gcn_b, x);

    // y1 = relu(x @ w1 + b1): 2048 ragged blocks -> 128 seg-sums -> finish
    k_matvec<<<MV1_GRID, 256, 0, stream>>>(x, w1, p1, MV1_BIGN, MV1_BIG, MV1_SMALL);
    k_sum16<<<128, 256, 0, stream>>>(p1, q1);
    k_finish128<<<4, 256, 0, stream>>>(q1, b1, y1);

    // y2 = relu(y1 @ w2 + b2): 256 blocks x 4 rows -> 16 seg-sums -> fused heads
    k_matvec<<<256, 256, 0, stream>>>(y1, w2, p2, 256, 4, 4);
    k_sum16<<<16, 256, 0, stream>>>(p2, q2);
    k_heads_f<<<1, 1024, 0, stream>>>(q2, b2, wv, bv, wa, ba, out);
}

// Round 5
// 230.133 us; speedup vs baseline: 2.2322x; 1.1221x over previous
//
#include <hip/hip_runtime.h>

#define N_NODES 4096
#define F_UAV 64
#define NOBS 262400
#define GCN_FLAT (N_NODES * F_UAV)   // 262144
#define HDIM 1024
#define N_ACT 64
#define N_EDGES 65536

typedef float f32x4 __attribute__((ext_vector_type(4)));
typedef float f32x2 __attribute__((ext_vector_type(2)));

// matvec1 partition: 2048 blocks, first 256 take 129 rows, rest 128.
#define MV1_GRID 2048
#define MV1_BIGN 256
#define MV1_BIG 129
#define MV1_SMALL 128

// ---- workspace layout (float offsets) ----
#define OFF_X      0                          // 262400
#define OFF_H      262400                     // 262144
#define OFF_DINV   (OFF_H + GCN_FLAT)         // 4096
#define OFF_DEG    (OFF_DINV + N_NODES)       // 4096 (int)
#define OFF_BASE   (OFF_DEG + N_NODES)        // 4096 (int)
#define OFF_CUR    (OFF_BASE + N_NODES)       // 4096 (int)
#define OFF_SSRC   (OFF_CUR + N_NODES)        // 65536 (int)
#define OFF_P1     (OFF_SSRC + N_EDGES)       // 2048*1024
#define OFF_Q1T    (OFF_P1 + 2048*1024)       // 1024*128
#define OFF_P2     (OFF_Q1T + 1024*128)       // 256*1024
#define OFF_Q2T    (OFF_P2 + 256*1024)        // 1024*16

// h = node_x @ gcn_w (4096x64 @ 64x64); blocks <256 also count edge in-degrees
// (deg[] pre-zeroed by hipMemsetAsync).
__global__ __launch_bounds__(256) void k_gcn_h(const float* __restrict__ nx,
                                               const float* __restrict__ w,
                                               const int* __restrict__ dst,
                                               float* __restrict__ h,
                                               int* __restrict__ deg) {
    __shared__ float sw[F_UAV * F_UAV];
    __shared__ float sx4[256];
    int tid = threadIdx.x;
    for (int i = tid; i < F_UAV * F_UAV; i += 256) sw[i] = w[i];
    sx4[tid] = nx[blockIdx.x * 256 + tid];
    if (blockIdx.x < 256) atomicAdd(&deg[dst[blockIdx.x * 256 + tid]], 1);
    __syncthreads();
    int r = tid >> 6, j = tid & 63;
    float acc = 0.f;
#pragma unroll
    for (int k = 0; k < F_UAV; ++k) acc += sx4[r * 64 + k] * sw[k * F_UAV + j];
    h[blockIdx.x * 256 + r * 64 + j] = acc;
}

// single block, 1024 threads: exclusive prefix over deg -> base, cursor;
// dinv = rsqrt(deg+1); copy obs tail into x.
__global__ __launch_bounds__(1024) void k_prefix(const int* __restrict__ deg,
                                                 int* __restrict__ base,
                                                 int* __restrict__ cursor,
                                                 float* __restrict__ dinv,
                                                 const float* __restrict__ obs,
                                                 float* __restrict__ x) {
    __shared__ int ssum[1024];
    int t = threadIdx.x;
    int d0 = deg[4 * t], d1 = deg[4 * t + 1], d2 = deg[4 * t + 2], d3 = deg[4 * t + 3];
    int local = d0 + d1 + d2 + d3;
    ssum[t] = local;
    __syncthreads();
    for (int off = 1; off < 1024; off <<= 1) {
        int v = (t >= off) ? ssum[t - off] : 0;
        __syncthreads();
        ssum[t] += v;
        __syncthreads();
    }
    int excl = ssum[t] - local;
    int b0 = excl, b1 = b0 + d0, b2 = b1 + d1, b3 = b2 + d2;
    base[4 * t] = b0;     cursor[4 * t] = b0;
    base[4 * t + 1] = b1; cursor[4 * t + 1] = b1;
    base[4 * t + 2] = b2; cursor[4 * t + 2] = b2;
    base[4 * t + 3] = b3; cursor[4 * t + 3] = b3;
    dinv[4 * t]     = rsqrtf((float)(d0 + 1));
    dinv[4 * t + 1] = rsqrtf((float)(d1 + 1));
    dinv[4 * t + 2] = rsqrtf((float)(d2 + 1));
    dinv[4 * t + 3] = rsqrtf((float)(d3 + 1));
    if (t < NOBS - GCN_FLAT) x[GCN_FLAT + t] = obs[GCN_FLAT + t];
}

// bucket placement: ssrc[slot] = src
__global__ void k_place(const int* __restrict__ src, const int* __restrict__ dst,
                        int* __restrict__ cursor, int* __restrict__ ssrc) {
    int e = blockIdx.x * 256 + threadIdx.x;
    if (e < N_EDGES) {
        int slot = atomicAdd(&cursor[dst[e]], 1);
        ssrc[slot] = src[e];
    }
}

// gather per destination node: one wave per node (4 waves/block)
__global__ __launch_bounds__(256) void k_gather(const int* __restrict__ base,
                                                const int* __restrict__ deg,
                                                const int* __restrict__ ssrc,
                                                const float* __restrict__ h,
                                                const float* __restrict__ dinv,
                                                const float* __restrict__ gb,
                                                float* __restrict__ x) {
    int tid = threadIdx.x;
    int n = blockIdx.x * 4 + (tid >> 6);
    int j = tid & 63;
    int lo = base[n], cnt = deg[n];
    int end = lo + cnt;
    float acc0 = 0.f, acc1 = 0.f;
    int i = lo;
    for (; i + 1 < end; i += 2) {
        int s0 = ssrc[i], s1 = ssrc[i + 1];
        acc0 += h[s0 * 64 + j] * dinv[s0];
        acc1 += h[s1 * 64 + j] * dinv[s1];
    }
    if (i < end) {
        int s = ssrc[i];
        acc0 += h[s * 64 + j] * dinv[s];
    }
    float dn = dinv[n];
    x[n * 64 + j] = (acc0 + acc1) * dn + h[n * 64 + j] * dn * dn + gb[j];
}

// partial mat-vec, ragged block row-ranges (tail-free grid).
__global__ __launch_bounds__(256) void k_matvec(const float* __restrict__ x,
                                                const float* __restrict__ W,
                                                float* __restrict__ part,
                                                int big_n, int big_sz, int small_sz) {
    __shared__ float sx[132];
    int tid = threadIdx.x;
    int b = blockIdx.x;
    int k0 = (b < big_n) ? b * big_sz : big_n * big_sz + (b - big_n) * small_sz;
    int cnt = (b < big_n) ? big_sz : small_sz;
    for (int i = tid; i < cnt; i += 256) sx[i] = x[k0 + i];
    __syncthreads();
    f32x4 acc = {0.f, 0.f, 0.f, 0.f};
    const f32x4* Wr = ((const f32x4*)W) + (size_t)k0 * (HDIM / 4) + tid;
    int kk = cnt & ~7;
    int k = 0;
    for (; k < kk; k += 8) {
#pragma unroll
        for (int u = 0; u < 8; ++u) {
            float xv = sx[k + u];
            f32x4 w = __builtin_nontemporal_load(&Wr[(size_t)(k + u) * (HDIM / 4)]);
            acc += xv * w;
        }
    }
    for (; k < cnt; ++k) acc += sx[k] * __builtin_nontemporal_load(&Wr[(size_t)k * (HDIM / 4)]);
    ((f32x4*)(part + (size_t)b * HDIM))[tid] = acc;
}

// stage-A: block s sums 16 consecutive partial rows, writes TRANSPOSED qT[j][s]
template <int NSEG>
__global__ __launch_bounds__(256) void k_sum16T(const float* __restrict__ part,
                                                float* __restrict__ qT) {
    int t = threadIdx.x, s = blockIdx.x;
    const f32x4* p = ((const f32x4*)part) + (size_t)s * 16 * (HDIM / 4) + t;
    f32x4 acc = {0.f, 0.f, 0.f, 0.f};
#pragma unroll
    for (int r = 0; r < 16; ++r) acc += p[(size_t)r * (HDIM / 4)];
#pragma unroll
    for (int u = 0; u < 4; ++u) qT[(size_t)(4 * t + u) * NSEG + s] = acc[u];
}

// fused: y1[4b..4b+4) = relu(b1 + rowsum of q1T), then 4-row matvec vs w2.
__global__ __launch_bounds__(256) void k_fin_mv2(const float* __restrict__ q1T,
                                                 const float* __restrict__ b1,
                                                 const float* __restrict__ w2,
                                                 float* __restrict__ p2) {
    __shared__ float s_y[4];
    int t = threadIdx.x, b = blockIdx.x;
    int w = t >> 6, l = t & 63;
    int j = 4 * b + w;
    f32x2 v = *(const f32x2*)&q1T[(size_t)j * 128 + 2 * l];
    float sm = v.x + v.y;
    for (int off = 32; off; off >>= 1) sm += __shfl_xor(sm, off);
    if (l == 0) s_y[w] = fmaxf(b1[j] + sm, 0.f);
    __syncthreads();
    f32x4 acc = {0.f, 0.f, 0.f, 0.f};
    const f32x4* Wr = ((const f32x4*)w2) + (size_t)(4 * b) * (HDIM / 4) + t;
#pragma unroll
    for (int i = 0; i < 4; ++i) acc += s_y[i] * Wr[(size_t)i * (HDIM / 4)];
    ((f32x4*)(p2 + (size_t)b * HDIM))[t] = acc;
}

// fused: y2 = relu(b2 + rowsum of q2T) then dueling heads. 1 block x 1024.
__global__ __launch_bounds__(1024) void k_heads_f(const float* __restrict__ q2T,
                                                  const float* __restrict__ b2,
                                                  const float* __restrict__ wv,
                                                  const float* __restrict__ bv,
                                                  const float* __restrict__ wa,
                                                  const float* __restrict__ ba,
                                                  float* __restrict__ out) {
    __shared__ float y2s[1024];
    __shared__ float s_adv[16][64];
    __shared__ float s_pv[1024];
    int t = threadIdx.x;
    float acc = b2[t];
#pragma unroll
    for (int s = 0; s < 16; ++s) acc += q2T[t * 16 + s];
    float y = fmaxf(acc, 0.f);
    y2s[t] = y;
    s_pv[t] = y * wv[t];
    __syncthreads();
    int g = t >> 6, a = t & 63;
    float pa = 0.f;
#pragma unroll 4
    for (int kk = 0; kk < 64; ++kk) pa += y2s[g * 64 + kk] * wa[(g * 64 + kk) * 64 + a];
    s_adv[g][a] = pa;
    __syncthreads();
    if (t < 64) {
        float adv = ba[a];
#pragma unroll
        for (int gg = 0; gg < 16; ++gg) adv += s_adv[gg][a];
        float v = 0.f;
#pragma unroll
        for (int i = 0; i < 16; ++i) v += s_pv[a + 64 * i];
        for (int off = 32; off; off >>= 1) v += __shfl_xor(v, off);
        float m = adv;
        for (int off = 32; off; off >>= 1) m += __shfl_xor(m, off);
        m *= (1.f / 64.f);
        out[a] = (v + bv[0]) + adv - m;
    }
}

extern "C" void kernel_launch(void* const* d_in, const int* in_sizes, int n_in,
                              void* d_out, int out_size, void* d_ws, size_t ws_size,
                              hipStream_t stream) {
    const float* node_x   = (const float*)d_in[0];
    const float* flat_obs = (const float*)d_in[1];
    const float* gcn_w    = (const float*)d_in[2];
    const float* gcn_b    = (const float*)d_in[3];
    const float* w1       = (const float*)d_in[4];
    const float* b1       = (const float*)d_in[5];
    const float* w2       = (const float*)d_in[6];
    const float* b2       = (const float*)d_in[7];
    const float* wv       = (const float*)d_in[8];
    const float* bv       = (const float*)d_in[9];
    const float* wa       = (const float*)d_in[10];
    const float* ba       = (const float*)d_in[11];
    const int*   ei       = (const int*)d_in[12];
    const int* src = ei;
    const int* dst = ei + N_EDGES;

    float* ws   = (float*)d_ws;
    float* x    = ws + OFF_X;
    float* h    = ws + OFF_H;
    float* dinv = ws + OFF_DINV;
    int*   deg  = (int*)(ws + OFF_DEG);
    int*   base = (int*)(ws + OFF_BASE);
    int*   cur  = (int*)(ws + OFF_CUR);
    int*   ssrc = (int*)(ws + OFF_SSRC);
    float* p1   = ws + OFF_P1;
    float* q1T  = ws + OFF_Q1T;
    float* p2   = ws + OFF_P2;
    float* q2T  = ws + OFF_Q2T;
    float* out  = (float*)d_out;

    hipMemsetAsync(deg, 0, N_NODES * sizeof(int), stream);
    k_gcn_h<<<N_NODES / 4, 256, 0, stream>>>(node_x, gcn_w, dst, h, deg);
    k_prefix<<<1, 1024, 0, stream>>>(deg, base, cur, dinv, flat_obs, x);
    k_place<<<N_EDGES / 256, 256, 0, stream>>>(src, dst, cur, ssrc);
    k_gather<<<N_NODES / 4, 256, 0, stream>>>(base, deg, ssrc, h, dinv, gcn_b, x);

    // y1/y2 pipeline
    k_matvec<<<MV1_GRID, 256, 0, stream>>>(x, w1, p1, MV1_BIGN, MV1_BIG, MV1_SMALL);
    k_sum16T<128><<<128, 256, 0, stream>>>(p1, q1T);
    k_fin_mv2<<<256, 256, 0, stream>>>(q1T, b1, w2, p2);
    k_sum16T<16><<<16, 256, 0, stream>>>(p2, q2T);
    k_heads_f<<<1, 1024, 0, stream>>>(q2T, b2, wv, bv, wa, ba, out);
}